// Round 12
// baseline (158.665 us; speedup 1.0000x reference)
//
#include <hip/hip_runtime.h>
#include <hip/hip_bf16.h>

#define BATCH 65536
#define DIN   128
#define DH    512
#define DOUT  128
#define ROWS  64

typedef __attribute__((ext_vector_type(4))) float f32x4;
typedef __attribute__((ext_vector_type(8))) short s16x8;

__device__ __forceinline__ ushort f32_to_bf16_rn(float f) {
    uint32_t u = __float_as_uint(f);
    uint32_t r = (u + 0x7FFFu + ((u >> 16) & 1u)) >> 16;
    return (ushort)r;
}
__device__ __forceinline__ float bf16_to_f32(ushort h) {
    return __uint_as_float(((uint32_t)h) << 16);
}
__device__ __forceinline__ f32x4 mfma16(s16x8 a, s16x8 b, f32x4 c) {
    return __builtin_amdgcn_mfma_f32_16x16x32_bf16(a, b, c, 0, 0, 0);
}
// two f32x4 -> one s16x8 (plain bf16 round-to-nearest, no lo residual)
__device__ __forceinline__ s16x8 cvt8(f32x4 v0, f32x4 v1) {
    s16x8 r;
#pragma unroll
    for (int j = 0; j < 4; ++j) r[j] = (short)f32_to_bf16_rn(v0[j]);
#pragma unroll
    for (int j = 0; j < 4; ++j) r[4 + j] = (short)f32_to_bf16_rn(v1[j]);
    return r;
}

// ---------------------------------------------------------------------------
// prep1: blk0 softmax; blk1..64 split B,C -> bf16 frag-linear (hi only);
// blk65..128: bc_f32 = b @ c ([128][128] f32).
// Fragment-linear: perm[(f*64+lane)*8+j] = M[k][col],
// k = ks*32+(lane>>4)*8+j, col = cg*16+(lane&15).
// B: f=cg*4+ks (cg<32). C: f=cg*16+ksg (cg<8, ksg<16).  [verified 8x]
// ---------------------------------------------------------------------------
__global__ void prep1_kernel(const float* __restrict__ a,
                             const float* __restrict__ b,
                             const float* __restrict__ c,
                             float* __restrict__ decay,
                             ushort* __restrict__ bhi,
                             ushort* __restrict__ chi,
                             float* __restrict__ bcf)
{
    const int t = threadIdx.x;
    if (blockIdx.x == 0) {
        __shared__ float red[256];
        float v0 = a[t], v1 = a[t + 256];
        red[t] = fmaxf(v0, v1);
        __syncthreads();
        for (int s = 128; s > 0; s >>= 1) {
            if (t < s) red[t] = fmaxf(red[t], red[t + s]);
            __syncthreads();
        }
        float M = red[0];
        __syncthreads();
        float e0 = expf(v0 - M), e1 = expf(v1 - M);
        red[t] = e0 + e1;
        __syncthreads();
        for (int s = 128; s > 0; s >>= 1) {
            if (t < s) red[t] += red[t + s];
            __syncthreads();
        }
        float S = red[0];
        decay[t]       = e0 / S;
        decay[t + 256] = e1 / S;
    } else if (blockIdx.x <= 64) {
        const int p = (blockIdx.x - 1) * 256 + t;
        const int mtx = p >> 13;
        const int q = p & 8191;
        const int f = q >> 6;
        const int l = q & 63;
        s16x8 hi;
        if (mtx == 0) {
            const int cg = f >> 2, ks = f & 3;
            const int col = cg * 16 + (l & 15);
            const int kbase = ks * 32 + (l >> 4) * 8;
#pragma unroll
            for (int j = 0; j < 8; ++j)
                hi[j] = (short)f32_to_bf16_rn(b[(size_t)(kbase + j) * DH + col]);
            *(s16x8*)(bhi + (size_t)q * 8) = hi;
        } else {
            const int cg = f >> 4, ks = f & 15;
            const int col = cg * 16 + (l & 15);
            const int kbase = ks * 32 + (l >> 4) * 8;
#pragma unroll
            for (int j = 0; j < 8; ++j)
                hi[j] = (short)f32_to_bf16_rn(c[(size_t)(kbase + j) * DOUT + col]);
            *(s16x8*)(chi + (size_t)q * 8) = hi;
        }
    } else {
        // bc = b @ c (f32). One output per thread; c reads L2-hot.
        const int i = (blockIdx.x - 65) * 2 + (t >> 7);
        const int j = t & 127;
        float acc = 0.f;
        for (int k = 0; k < DH; ++k)
            acc = fmaf(b[(size_t)i * DH + k], c[(size_t)k * DOUT + j], acc);
        bcf[i * DOUT + j] = acc;
    }
}

// ---------------------------------------------------------------------------
// prep2: bc_f32 -> bf16 frag-linear (K=128: f = cg*4+ks, cg<8).
// ---------------------------------------------------------------------------
__global__ void prep2_kernel(const float* __restrict__ bcf,
                             ushort* __restrict__ bch)
{
    const int p = blockIdx.x * 256 + threadIdx.x;   // [0, 2048)
    const int f = p >> 6, l = p & 63;
    const int cg = f >> 2, ks = f & 3;
    const int col = cg * 16 + (l & 15);
    const int kbase = ks * 32 + (l >> 4) * 8;
    s16x8 hi;
#pragma unroll
    for (int j = 0; j < 8; ++j)
        hi[j] = (short)f32_to_bf16_rn(bcf[(size_t)(kbase + j) * DOUT + col]);
    *(s16x8*)(bch + (size_t)p * 8) = hi;
}

// ---------------------------------------------------------------------------
// fused v8: plain-bf16 (tolerance 4.0 >> bf16 error ~1), ROWS=64, bc-algebra.
//   xn = u@b + decay*x ; out = (decay*x)@c + u@bc.
// Block 64 rows (grid 1024), 4 waves, 8 chunks x 64 cols. LDS 32KB:
// A(u bf16) 16KB + X dbuf 2x8KB -> 5 blocks/CU. Per chunk:
//   stage X[ct&1] = bf16(decay*x) (coalesced 64B/thread, prefetched regs),
//   ONE __syncthreads, then GEMM1 (u@B, 16 MFMA, wave=16 cols, B-frag
//   reuse x4), xn = acc1 + X-readback, GEMM2 (X@C, 16 MFMA, K=64).
// Final: acc2 += u@bc (32 MFMA), out store. MFMA 3x cheaper than split-3.
// ---------------------------------------------------------------------------
__global__ __launch_bounds__(256, 4)
void rnn_fused(const float* __restrict__ u, const float* __restrict__ x,
               const float* __restrict__ decay,
               const ushort* __restrict__ bhi, const ushort* __restrict__ chi,
               const ushort* __restrict__ bch,
               float* __restrict__ xn, float* __restrict__ out)
{
    __shared__ __align__(16) char smem[32768];
    ushort* Ah = (ushort*)smem;              // [64][128] bf16, swz, 16KB

    const int t = threadIdx.x;
    const int lane = t & 63, w = t >> 6;
    const int cl = lane & 15, hk = lane >> 4;
    const int row0 = blockIdx.x * ROWS;

    {   // stage A: u[64][128] f32 -> bf16 swizzled; 128B/thread coalesced
        const int r = t >> 2;
        const int kb = (t & 3) * 32;
#pragma unroll
        for (int i = 0; i < 4; ++i) {
            const float* src = u + (size_t)(row0 + r) * DIN + kb + i * 8;
            f32x4 v0 = *(const f32x4*)src;
            f32x4 v1 = *(const f32x4*)(src + 4);
            const int byte = (r * 256 + (kb + i * 8) * 2) ^ ((r & 7) << 4);
            *(s16x8*)((char*)Ah + byte) = cvt8(v0, v1);
        }
    }

    // x staging geometry: thread covers row sr, 16 cols at skb of each chunk
    const int sr = t >> 2, skb = (t & 3) * 16;
    const float* xrow = x + (size_t)(row0 + sr) * DH + skb;

    // prologue: prefetch chunk-0 x (4 x f32x4)
    f32x4 xr[4];
#pragma unroll
    for (int i = 0; i < 4; ++i) xr[i] = *(const f32x4*)(xrow + i * 4);

    f32x4 acc2[4][2];
#pragma unroll
    for (int mf = 0; mf < 4; ++mf)
#pragma unroll
        for (int nf = 0; nf < 2; ++nf)
            acc2[mf][nf] = (f32x4){0.f, 0.f, 0.f, 0.f};

    for (int ct = 0; ct < 8; ++ct) {
        char* Xh = smem + 16384 + (ct & 1) * 8192;   // [64][64] bf16, swz, 8KB

        // ---- stage X = bf16(decay * x) from prefetched regs
        {
            const int dbase = ct * 64 + skb;
            const f32x4 d0 = *(const f32x4*)&decay[dbase];
            const f32x4 d1 = *(const f32x4*)&decay[dbase + 4];
            const f32x4 d2 = *(const f32x4*)&decay[dbase + 8];
            const f32x4 d3 = *(const f32x4*)&decay[dbase + 12];
            const int sb0 = (sr * 128 + skb * 2) ^ ((sr & 7) << 4);
            const int sb1 = (sr * 128 + (skb + 8) * 2) ^ ((sr & 7) << 4);
            *(s16x8*)(Xh + sb0) = cvt8(xr[0] * d0, xr[1] * d1);
            *(s16x8*)(Xh + sb1) = cvt8(xr[2] * d2, xr[3] * d3);
        }

        // ---- prefetch next chunk's x (stays in flight across barrier)
        if (ct < 7) {
#pragma unroll
            for (int i = 0; i < 4; ++i)
                xr[i] = *(const f32x4*)(xrow + (ct + 1) * 64 + i * 4);
        }

        __syncthreads();   // A (first iter) + X[ct&1] visible

        // ---- GEMM1: acc1 = u @ B-chunk (wave cols = (ct*4+w)*16 .. +16)
        f32x4 acc1[4];
#pragma unroll
        for (int mf = 0; mf < 4; ++mf) acc1[mf] = (f32x4){0.f, 0.f, 0.f, 0.f};
#pragma unroll
        for (int ks = 0; ks < 4; ++ks) {
            const int ko = ks * 32 + hk * 8;
            s16x8 ah[4];
#pragma unroll
            for (int mf = 0; mf < 4; ++mf) {
                const int r = mf * 16 + cl;
                const int byte = (r * 256 + ko * 2) ^ ((r & 7) << 4);
                ah[mf] = *(const s16x8*)((const char*)Ah + byte);
            }
            const size_t fB = (size_t)((ct * 4 + w) * 4 + ks) * 512 + lane * 8;
            s16x8 bh = *(const s16x8*)(bhi + fB);
#pragma unroll
            for (int mf = 0; mf < 4; ++mf) acc1[mf] = mfma16(ah[mf], bh, acc1[mf]);
        }

        // ---- xn = acc1 + (dv*x) read back from X LDS (C/D positions)
        {
            const int col = ct * 64 + w * 16 + cl;
#pragma unroll
            for (int mf = 0; mf < 4; ++mf) {
#pragma unroll
                for (int j = 0; j < 4; ++j) {
                    const int lrow = mf * 16 + 4 * hk + j;
                    const int cb = (lrow * 128 + (w * 16 + cl) * 2) ^ ((lrow & 7) << 4);
                    const float dvx = bf16_to_f32(*(const ushort*)(Xh + cb));
                    xn[(size_t)(row0 + lrow) * DH + col] = acc1[mf][j] + dvx;
                }
            }
        }

        // ---- GEMM2: acc2 += X @ C-chunk (K=64, ksg = ct*2+ks2)
#pragma unroll
        for (int ks2 = 0; ks2 < 2; ++ks2) {
            s16x8 xh[4];
#pragma unroll
            for (int mf = 0; mf < 4; ++mf) {
                const int lrow = mf * 16 + cl;
                const int cb = (lrow * 128 + (ks2 * 32 + hk * 8) * 2) ^ ((lrow & 7) << 4);
                xh[mf] = *(const s16x8*)(Xh + cb);
            }
            const int ksg = ct * 2 + ks2;
#pragma unroll
            for (int nf2 = 0; nf2 < 2; ++nf2) {
                const size_t fC = (size_t)((w * 2 + nf2) * 16 + ksg) * 512 + lane * 8;
                s16x8 ch = *(const s16x8*)(chi + fC);
#pragma unroll
                for (int mf = 0; mf < 4; ++mf)
                    acc2[mf][nf2] = mfma16(xh[mf], ch, acc2[mf][nf2]);
            }
        }
    }

    // ---- final: acc2 += u @ bc (K=128, wave out-cols w*32 .. +32)
#pragma unroll
    for (int ks = 0; ks < 4; ++ks) {
        const int ko = ks * 32 + hk * 8;
        s16x8 ah[4];
#pragma unroll
        for (int mf = 0; mf < 4; ++mf) {
            const int r = mf * 16 + cl;
            const int byte = (r * 256 + ko * 2) ^ ((r & 7) << 4);
            ah[mf] = *(const s16x8*)((const char*)Ah + byte);
        }
#pragma unroll
        for (int nf2 = 0; nf2 < 2; ++nf2) {
            const size_t fbc = (size_t)((w * 2 + nf2) * 4 + ks) * 512 + lane * 8;
            s16x8 h2 = *(const s16x8*)(bch + fbc);
#pragma unroll
            for (int mf = 0; mf < 4; ++mf)
                acc2[mf][nf2] = mfma16(ah[mf], h2, acc2[mf][nf2]);
        }
    }

    // ---- store out[64 x 128]; wave cols [w*32, +32)
#pragma unroll
    for (int nf2 = 0; nf2 < 2; ++nf2) {
        const int ocol = w * 32 + nf2 * 16 + cl;
#pragma unroll
        for (int mf = 0; mf < 4; ++mf)
#pragma unroll
            for (int j = 0; j < 4; ++j)
                out[(size_t)(row0 + mf * 16 + 4 * hk + j) * DOUT + ocol] =
                    acc2[mf][nf2][j];
    }
}

extern "C" void kernel_launch(void* const* d_in, const int* in_sizes, int n_in,
                              void* d_out, int out_size, void* d_ws, size_t ws_size,
                              hipStream_t stream)
{
    const float* x = (const float*)d_in[0];
    const float* u = (const float*)d_in[1];
    const float* a = (const float*)d_in[2];
    const float* b = (const float*)d_in[3];
    const float* c = (const float*)d_in[4];

    float* xn  = (float*)d_out;                       // [BATCH][DH]
    float* out = xn + (size_t)BATCH * DH;             // [BATCH][DOUT]

    char* ws = (char*)d_ws;
    float*  decay = (float*)ws;                       // 512 f32
    ushort* bhi = (ushort*)(ws + 4096);               // 128KB
    ushort* chi = bhi + 128 * 512;                    // 128KB
    float*  bcf = (float*)(ws + 4096 + 2 * 131072);   // 64KB
    ushort* bch = (ushort*)(ws + 4096 + 2 * 131072 + 65536);  // 32KB

    prep1_kernel<<<dim3(129), dim3(256), 0, stream>>>(a, b, c, decay, bhi, chi, bcf);
    prep2_kernel<<<dim3(8), dim3(256), 0, stream>>>(bcf, bch);
    rnn_fused<<<dim3(BATCH / ROWS), dim3(256), 0, stream>>>(u, x, decay, bhi, chi, bch, xn, out);
}

// Round 13
// 108.478 us; speedup vs baseline: 1.4626x; 1.4626x over previous
//
#include <hip/hip_runtime.h>
#include <hip/hip_bf16.h>

#define BATCH 65536
#define DIN   128
#define DH    512
#define DOUT  128
#define ROWS  32

typedef __attribute__((ext_vector_type(4))) float f32x4;
typedef __attribute__((ext_vector_type(8))) short s16x8;

__device__ __forceinline__ ushort f32_to_bf16_rn(float f) {
    uint32_t u = __float_as_uint(f);
    uint32_t r = (u + 0x7FFFu + ((u >> 16) & 1u)) >> 16;
    return (ushort)r;
}
__device__ __forceinline__ float bf16_to_f32(ushort h) {
    return __uint_as_float(((uint32_t)h) << 16);
}
__device__ __forceinline__ f32x4 mfma16(s16x8 a, s16x8 b, f32x4 c) {
    return __builtin_amdgcn_mfma_f32_16x16x32_bf16(a, b, c, 0, 0, 0);
}
// two f32x4 -> one s16x8 (plain bf16 RN; tolerance 8.0 >> bf16 GEMM error ~1)
__device__ __forceinline__ s16x8 cvt8(f32x4 v0, f32x4 v1) {
    s16x8 r;
#pragma unroll
    for (int j = 0; j < 4; ++j) r[j] = (short)f32_to_bf16_rn(v0[j]);
#pragma unroll
    for (int j = 0; j < 4; ++j) r[4 + j] = (short)f32_to_bf16_rn(v1[j]);
    return r;
}

// ---------------------------------------------------------------------------
// prep: blk0 softmax(a); blk1..64 split B,C -> bf16 frag-linear.
// perm[(f*64+lane)*8+j] = M[k][col], k = ks*32+(lane>>4)*8+j,
// col = cg*16+(lane&15). B: f=cg*4+ks (cg<32). C: f=cg*16+ksg (cg<8,ksg<16).
// [layouts verified 9 rounds running]
// ---------------------------------------------------------------------------
__global__ void prep_kernel(const float* __restrict__ a,
                            const float* __restrict__ b,
                            const float* __restrict__ c,
                            float* __restrict__ decay,
                            ushort* __restrict__ bhi,
                            ushort* __restrict__ chi)
{
    const int t = threadIdx.x;
    if (blockIdx.x == 0) {
        __shared__ float red[256];
        float v0 = a[t], v1 = a[t + 256];
        red[t] = fmaxf(v0, v1);
        __syncthreads();
        for (int s = 128; s > 0; s >>= 1) {
            if (t < s) red[t] = fmaxf(red[t], red[t + s]);
            __syncthreads();
        }
        float M = red[0];
        __syncthreads();
        float e0 = expf(v0 - M), e1 = expf(v1 - M);
        red[t] = e0 + e1;
        __syncthreads();
        for (int s = 128; s > 0; s >>= 1) {
            if (t < s) red[t] += red[t + s];
            __syncthreads();
        }
        float S = red[0];
        decay[t]       = e0 / S;
        decay[t + 256] = e1 / S;
    } else {
        const int p = (blockIdx.x - 1) * 256 + t;
        const int mtx = p >> 13;
        const int q = p & 8191;
        const int f = q >> 6;
        const int l = q & 63;
        s16x8 hi;
        if (mtx == 0) {
            const int cg = f >> 2, ks = f & 3;
            const int col = cg * 16 + (l & 15);
            const int kbase = ks * 32 + (l >> 4) * 8;
#pragma unroll
            for (int j = 0; j < 8; ++j)
                hi[j] = (short)f32_to_bf16_rn(b[(size_t)(kbase + j) * DH + col]);
            *(s16x8*)(bhi + (size_t)q * 8) = hi;
        } else {
            const int cg = f >> 4, ks = f & 15;
            const int col = cg * 16 + (l & 15);
            const int kbase = ks * 32 + (l >> 4) * 8;
#pragma unroll
            for (int j = 0; j < 8; ++j)
                hi[j] = (short)f32_to_bf16_rn(c[(size_t)(kbase + j) * DOUT + col]);
            *(s16x8*)(chi + (size_t)q * 8) = hi;
        }
    }
}

// ---------------------------------------------------------------------------
// fused v9: R5's exact structure/patterns (best measured: FETCH 86MB,
// WRITE 164MB), numerics swapped to plain bf16 (1/3 MFMA, no lo streams).
// Block = 32 rows, 4 waves, 8 chunks x 64 cols. LDS 16KB (A 8KB + X dbuf
// 2x4KB) + VGPR<=85 + launch_bounds(256,6) -> target 6 blocks/CU.
// Per chunk: prefetch x (C/D pattern) -> GEMM1 (u@B, 16 MFMA, wave=16
// cols) -> barrier -> epilogue {xn = acc1+dv*x store; X = bf16(xn) to
// LDS} -> barrier -> GEMM2 (X@C, K=64, 8 MFMA, wave out-cols w*32..+32).
// ---------------------------------------------------------------------------
__global__ __launch_bounds__(256, 6)
void rnn_fused(const float* __restrict__ u, const float* __restrict__ x,
               const float* __restrict__ decay,
               const ushort* __restrict__ bhi, const ushort* __restrict__ chi,
               float* __restrict__ xn, float* __restrict__ out)
{
    __shared__ __align__(16) char smem[16384];
    ushort* Ah = (ushort*)smem;             // [32][128] bf16, swz, 8KB

    const int t = threadIdx.x;
    const int lane = t & 63, wc = t >> 6;
    const int cl = lane & 15, hk = lane >> 4;
    const int row0 = blockIdx.x * ROWS;

    {   // stage A: u[32][128] f32 -> bf16 swizzled; 64B/thread coalesced
        const int r = t >> 3;
        const int kb = (t & 7) * 2;
#pragma unroll
        for (int i = 0; i < 2; ++i) {
            const float* src = u + (size_t)(row0 + r) * DIN + (kb + i) * 8;
            f32x4 v0 = *(const f32x4*)src;
            f32x4 v1 = *(const f32x4*)(src + 4);
            const int byte = (r * 256 + (kb + i) * 16) ^ ((r & 7) << 4);
            *(s16x8*)((char*)Ah + byte) = cvt8(v0, v1);
        }
    }
    __syncthreads();

    f32x4 acc2[2][2];
#pragma unroll
    for (int mf = 0; mf < 2; ++mf)
#pragma unroll
        for (int nf = 0; nf < 2; ++nf)
            acc2[mf][nf] = (f32x4){0.f, 0.f, 0.f, 0.f};

    for (int ct = 0; ct < 8; ++ct) {
        char* Xh = smem + 8192 + (ct & 1) * 4096;   // [32][64] bf16, swz, 4KB

        // ---- prefetch x + decay for this chunk (hides under GEMM1)
        const int col = ct * 64 + wc * 16 + cl;
        const float dvc = decay[col];
        float xv[2][4];
#pragma unroll
        for (int mf = 0; mf < 2; ++mf)
#pragma unroll
            for (int j = 0; j < 4; ++j)
                xv[mf][j] = x[(size_t)(row0 + mf * 16 + 4 * hk + j) * DH + col];

        // ---- GEMM1: acc1 = u @ B-chunk; wave tile 32 rows x 16 cols
        f32x4 acc1[2];
        acc1[0] = (f32x4){0.f, 0.f, 0.f, 0.f};
        acc1[1] = (f32x4){0.f, 0.f, 0.f, 0.f};
#pragma unroll
        for (int ks = 0; ks < 4; ++ks) {
            const int ko = ks * 32 + hk * 8;
            s16x8 ah[2];
#pragma unroll
            for (int mf = 0; mf < 2; ++mf) {
                const int r = mf * 16 + cl;
                const int byte = (r * 256 + ko * 2) ^ ((r & 7) << 4);
                ah[mf] = *(const s16x8*)((const char*)Ah + byte);
            }
            const size_t fB = (size_t)((ct * 4 + wc) * 4 + ks) * 512 + lane * 8;
            s16x8 bh = *(const s16x8*)(bhi + fB);
#pragma unroll
            for (int mf = 0; mf < 2; ++mf) acc1[mf] = mfma16(ah[mf], bh, acc1[mf]);
        }

        __syncthreads();   // prev chunk's GEMM2 X-reads complete (WAR)

        // ---- epilogue: xn = acc1 + decay*x; store + bf16 into X LDS
#pragma unroll
        for (int mf = 0; mf < 2; ++mf) {
#pragma unroll
            for (int j = 0; j < 4; ++j) {
                const int rl = mf * 16 + 4 * hk + j;
                const float v = acc1[mf][j] + dvc * xv[mf][j];
                xn[(size_t)(row0 + rl) * DH + col] = v;
                const int cbyte = (rl * 128 + (wc * 16 + cl) * 2) ^ ((rl & 7) << 4);
                *(ushort*)(Xh + cbyte) = f32_to_bf16_rn(v);
            }
        }
        __syncthreads();   // X visible to all waves

        // ---- GEMM2: out += X @ C-chunk; wave tile 32 rows x 32 cols, K=64
#pragma unroll
        for (int ks2 = 0; ks2 < 2; ++ks2) {
            const int ko = ks2 * 32 + hk * 8;
            s16x8 ah2[2];
#pragma unroll
            for (int mf = 0; mf < 2; ++mf) {
                const int r = mf * 16 + cl;
                const int byte = (r * 128 + ko * 2) ^ ((r & 7) << 4);
                ah2[mf] = *(const s16x8*)((const char*)Xh + byte);
            }
            const int ksg = ct * 2 + ks2;
#pragma unroll
            for (int nf = 0; nf < 2; ++nf) {
                const size_t fC = (size_t)((wc * 2 + nf) * 16 + ksg) * 512 + lane * 8;
                s16x8 ch = *(const s16x8*)(chi + fC);
#pragma unroll
                for (int mf = 0; mf < 2; ++mf)
                    acc2[mf][nf] = mfma16(ah2[mf], ch, acc2[mf][nf]);
            }
        }
    }

    // ---- final: store out[32 x 128]; wave covers cols [wc*32, +32)
#pragma unroll
    for (int nf = 0; nf < 2; ++nf) {
        const int ocol = wc * 32 + nf * 16 + cl;
#pragma unroll
        for (int mf = 0; mf < 2; ++mf) {
#pragma unroll
            for (int j = 0; j < 4; ++j) {
                const int rl = mf * 16 + 4 * hk + j;
                out[(size_t)(row0 + rl) * DOUT + ocol] = acc2[mf][nf][j];
            }
        }
    }
}

extern "C" void kernel_launch(void* const* d_in, const int* in_sizes, int n_in,
                              void* d_out, int out_size, void* d_ws, size_t ws_size,
                              hipStream_t stream)
{
    const float* x = (const float*)d_in[0];
    const float* u = (const float*)d_in[1];
    const float* a = (const float*)d_in[2];
    const float* b = (const float*)d_in[3];
    const float* c = (const float*)d_in[4];

    float* xn  = (float*)d_out;                       // [BATCH][DH]
    float* out = xn + (size_t)BATCH * DH;             // [BATCH][DOUT]

    char* ws = (char*)d_ws;
    float*  decay = (float*)ws;                       // 512 f32
    ushort* bhi = (ushort*)(ws + 4096);               // 128KB frag-linear B
    ushort* chi = bhi + 128 * 512;                    // 128KB frag-linear C

    prep_kernel<<<dim3(65), dim3(256), 0, stream>>>(a, b, c, decay, bhi, chi);
    rnn_fused<<<dim3(BATCH / ROWS), dim3(256), 0, stream>>>(u, x, decay, bhi, chi, xn, out);
}